// Round 1
// baseline (109.851 us; speedup 1.0000x reference)
//
#include <hip/hip_runtime.h>
#include <hip/hip_bf16.h>

typedef __attribute__((ext_vector_type(4))) float f32x4;
typedef __attribute__((ext_vector_type(8))) short bf16x8;
typedef unsigned short ushort_t;

#define T_LEN 8192
#define N_REFL 8187        // last valid A/L base index (arrays have 8188 elems)
#define TS 64              // output positions per block
#define WIN 80             // phase window positions computed per block
#define XW 88              // staged x positions per block
#define XSTRIDE 72         // ushorts per xs row (64 ch + 8 pad)
#define PSTRIDE 65         // floats per phase row (64 o + 1 pad)
#define PH_ELEMS (WIN * PSTRIDE)   // 5200 floats per phase

__device__ __forceinline__ ushort_t f2bf(float f) {
    union { float f; unsigned u; } a; a.f = f;
    unsigned r = a.u + 0x7FFF + ((a.u >> 16) & 1);
    return (ushort_t)(r >> 16);
}

// Repack w (128, 64, 13) f32 -> wbf[tap][o][c] bf16
__global__ void convert_w_kernel(const float* __restrict__ w, ushort_t* __restrict__ wbf) {
    int idx = blockIdx.x * 256 + threadIdx.x;
    if (idx >= 128 * 64 * 13) return;
    int tap = idx % 13;
    int c   = (idx / 13) & 63;
    int o   = idx / (13 * 64);
    wbf[(tap * 128 + o) * 64 + c] = f2bf(w[idx]);
}

__global__ __launch_bounds__(256, 2)
void fused_trconv_kernel(const float* __restrict__ x, const ushort_t* __restrict__ wbf,
                         const float* __restrict__ bias, float* __restrict__ out) {
    // Phase buffers (written after K-loop) alias the x staging buffer (dead by then).
    __shared__ float smem_f[3 * PH_ELEMS];   // 62,400 B
    ushort_t* xs = (ushort_t*)smem_f;        // [XW][XSTRIDE] bf16, first 12,672 B

    const int bx   = blockIdx.x;
    const int tile = bx & 127;
    const int g    = (bx >> 7) & 1;
    const int b    = bx >> 8;
    const int t0   = tile * TS;
    const int mbase = t0 - 8;
    const int tid  = threadIdx.x;

    // ---------------- stage x[group ch][mbase .. mbase+87] -> LDS bf16 [pos][ch] ----------------
    const float* xg = x + ((size_t)b * 128 + (size_t)g * 64) * T_LEN;
    for (int cid = tid; cid < 64 * (XW / 4); cid += 256) {
        int c  = cid & 63;
        int kc = cid >> 6;          // 0..21
        int s0 = kc * 4;
        int m0 = mbase + s0;
        const float* src = xg + (size_t)c * T_LEN + m0;
        float v0, v1, v2, v3;
        if (m0 >= 0 && m0 + 3 < T_LEN) {
            float4 v = *(const float4*)src;
            v0 = v.x; v1 = v.y; v2 = v.z; v3 = v.w;
        } else {
            v0 = (m0 + 0 >= 0 && m0 + 0 < T_LEN) ? src[0] : 0.f;
            v1 = (m0 + 1 >= 0 && m0 + 1 < T_LEN) ? src[1] : 0.f;
            v2 = (m0 + 2 >= 0 && m0 + 2 < T_LEN) ? src[2] : 0.f;
            v3 = (m0 + 3 >= 0 && m0 + 3 < T_LEN) ? src[3] : 0.f;
        }
        ushort_t* dst = xs + s0 * XSTRIDE + c;
        dst[0 * XSTRIDE] = f2bf(v0);
        dst[1 * XSTRIDE] = f2bf(v1);
        dst[2 * XSTRIDE] = f2bf(v2);
        dst[3 * XSTRIDE] = f2bf(v3);
    }
    __syncthreads();

    // ---------------- MFMA: A (taps 3u), L0 (3u+2), L1 (3u+1) over 80-pos window ----------------
    const int lane = tid & 63;
    const int wv   = tid >> 6;       // wave id -> o-tile (16 out-chs)
    const int row  = lane & 15;      // A row (position) == B col (out-ch)
    const int kb   = lane >> 4;      // k-block 0..3

    f32x4 acc[3][5];
    #pragma unroll
    for (int p = 0; p < 3; ++p)
        #pragma unroll
        for (int q = 0; q < 5; ++q)
            acc[p][q] = (f32x4){0.f, 0.f, 0.f, 0.f};

    const int wo = g * 64 + wv * 16 + row;   // global out-channel this lane's B-col maps to

    #pragma unroll
    for (int u = 0; u < 5; ++u) {
        #pragma unroll
        for (int h = 0; h < 2; ++h) {
            bf16x8 wf0 = *(const bf16x8*)(wbf + ((3 * u + 0) * 128 + wo) * 64 + h * 32 + kb * 8);
            bf16x8 wf1 = {}, wf2 = {};
            if (u < 4) {
                wf1 = *(const bf16x8*)(wbf + ((3 * u + 2) * 128 + wo) * 64 + h * 32 + kb * 8);
                wf2 = *(const bf16x8*)(wbf + ((3 * u + 1) * 128 + wo) * 64 + h * 32 + kb * 8);
            }
            #pragma unroll
            for (int q = 0; q < 5; ++q) {
                const bf16x8 xa = *(const bf16x8*)(xs + (16 * q + row + u) * XSTRIDE + h * 32 + kb * 8);
                acc[0][q] = __builtin_amdgcn_mfma_f32_16x16x32_bf16(xa, wf0, acc[0][q], 0, 0, 0);
                if (u < 4) {
                    acc[1][q] = __builtin_amdgcn_mfma_f32_16x16x32_bf16(xa, wf1, acc[1][q], 0, 0, 0);
                    acc[2][q] = __builtin_amdgcn_mfma_f32_16x16x32_bf16(xa, wf2, acc[2][q], 0, 0, 0);
                }
            }
        }
    }
    __syncthreads();   // all waves done reading xs; safe to overwrite with phase data

    // ---------------- dump phase tiles to LDS: ph[p][s][o_local] ----------------
    #pragma unroll
    for (int p = 0; p < 3; ++p)
        #pragma unroll
        for (int q = 0; q < 5; ++q)
            #pragma unroll
            for (int r = 0; r < 4; ++r)
                smem_f[p * PH_ELEMS + (16 * q + kb * 4 + r) * PSTRIDE + wv * 16 + row] = acc[p][q][r];
    __syncthreads();

    // ---------------- elementwise epilogue ----------------
    const int tl = tid & 63;
    const int gi = tid >> 6;
    const int t  = t0 + tl;

    int  s5[5];
    bool in5[5];
    #pragma unroll
    for (int dt = 0; dt < 5; ++dt) {
        int tp = t + dt - 2;
        in5[dt] = ((unsigned)tp < (unsigned)T_LEN);
        int idx = tp - 2;
        idx = (idx < 0) ? -idx : idx;
        idx = (idx > N_REFL) ? (2 * N_REFL - idx) : idx;
        s5[dt] = idx - mbase;
    }
    const int sC = s5[2];   // refl(t-2): shared by xm and the L reads

    const float* phA  = smem_f;
    const float* phL0 = smem_f + PH_ELEMS;
    const float* phL1 = smem_f + 2 * PH_ELEMS;
    float* outp = out + ((size_t)b * 128 + (size_t)g * 64) * T_LEN + t;
    const float* bp = bias + g * 64;

    for (int i = 0; i < 16; ++i) {
        int o = gi + 4 * i;
        float bo = bp[o];
        float xm = phA[sC * PSTRIDE + o] + bo;
        float u = -1e30f;
        #pragma unroll
        for (int dt = 0; dt < 5; ++dt) {
            float v = phA[s5[dt] * PSTRIDE + o] + bo;
            u = fmaxf(u, in5[dt] ? v : 0.f);
        }
        float l0  = phL0[sC * PSTRIDE + o];
        float l0p = phL0[(sC + 1) * PSTRIDE + o];
        float l1  = phL1[sC * PSTRIDE + o];
        float l1p = phL1[(sC + 1) * PSTRIDE + o];
        float a = 2.f * xm + u;
        float d0 = l0p - l0;
        a += d0 / (1.f + __expf(-1.702f * d0)) + (l0p + l0 + 2.f * bo);
        float d1 = l1p - l1;
        a += d1 / (1.f + __expf(-1.702f * d1)) + (l1p + l1 + 2.f * bo);
        outp[(size_t)o * T_LEN] = a;
    }
}

extern "C" void kernel_launch(void* const* d_in, const int* in_sizes, int n_in,
                              void* d_out, int out_size, void* d_ws, size_t ws_size,
                              hipStream_t stream) {
    const float* x    = (const float*)d_in[0];
    const float* w    = (const float*)d_in[1];
    const float* bias = (const float*)d_in[2];
    float* out        = (float*)d_out;
    ushort_t* wbf     = (ushort_t*)d_ws;    // 13*128*64*2 = 212,992 B

    hipLaunchKernelGGL(convert_w_kernel, dim3(416), dim3(256), 0, stream, w, wbf);
    hipLaunchKernelGGL(fused_trconv_kernel, dim3(16 * 2 * 128), dim3(256), 0, stream,
                       x, wbf, bias, out);
}

// Round 2
// 97.475 us; speedup vs baseline: 1.1270x; 1.1270x over previous
//
#include <hip/hip_runtime.h>
#include <hip/hip_bf16.h>

typedef __attribute__((ext_vector_type(4))) float f32x4;
typedef __attribute__((ext_vector_type(8))) short bf16x8;
typedef unsigned short ushort_t;

#define T_LEN 8192
#define N_REFL 8187              // last valid phase index (phase arrays have 8188 elems)
#define TS 64                    // output positions per block
#define WIN 80                   // phase window positions per block
#define XW 88                    // staged x positions per block
#define POSTRIDE 66              // u16 per phase row (64 o + 2 pad) -> word stride 33 (odd)
#define PH_U16 (WIN * POSTRIDE)  // 5280 u16 per phase

__device__ __forceinline__ ushort_t f2bf(float f) {
    union { float f; unsigned u; } a; a.f = f;
    unsigned r = a.u + 0x7FFF + ((a.u >> 16) & 1);
    return (ushort_t)(r >> 16);
}

union bf2u { __hip_bfloat162 h; unsigned u; ushort_t s[2]; };

__device__ __forceinline__ unsigned pack_bf2(float a, float b) {
    bf2u x; x.h = __float22bfloat162_rn(make_float2(a, b));  // v_cvt_pk_bf16_f32
    return x.u;
}
__device__ __forceinline__ float bflo(unsigned u) {
    union { unsigned u; float f; } x; x.u = u << 16; return x.f;
}
__device__ __forceinline__ float bfhi(unsigned u) {
    union { unsigned u; float f; } x; x.u = u & 0xffff0000u; return x.f;
}
__device__ __forceinline__ float qgelu(float d) {
    return __fdividef(d, 1.f + __expf(-1.702f * d));
}

// Repack w (128, 64, 13) f32 -> wbf[tap][o][c] bf16
__global__ void convert_w_kernel(const float* __restrict__ w, ushort_t* __restrict__ wbf) {
    int idx = blockIdx.x * 256 + threadIdx.x;
    if (idx >= 128 * 64 * 13) return;
    int tap = idx % 13;
    int c   = (idx / 13) & 63;
    int o   = idx / (13 * 64);
    wbf[(tap * 128 + o) * 64 + c] = f2bf(w[idx]);
}

__global__ __launch_bounds__(256, 4)
void fused_trconv_kernel(const float* __restrict__ x, const ushort_t* __restrict__ wbf,
                         const float* __restrict__ bias, float* __restrict__ out) {
    // Phases (bf16, bias-folded) alias the x staging buffer (dead after K-loop).
    __shared__ ushort_t smem[3 * PH_U16];   // 31,680 B -> 5 blocks/CU LDS-wise
    ushort_t* xs = smem;                    // [XW][64] bf16, XOR-swizzled, 11,264 B

    const int bx    = blockIdx.x;
    const int tile  = bx & 127;
    const int g     = (bx >> 7) & 1;
    const int b     = bx >> 8;
    const int t0    = tile * TS;
    const int mbase = t0 - 8;
    const int tid   = threadIdx.x;

    // ---------------- stage x[group ch][mbase .. mbase+87] -> LDS bf16 [pos][ch] ----------------
    const float* xg = x + ((size_t)b * 128 + (size_t)g * 64) * T_LEN;
    for (int cid = tid; cid < 64 * (XW / 4); cid += 256) {
        int c  = cid & 63;
        int kc = cid >> 6;          // 0..21 (wave-uniform per iteration)
        int s0 = kc * 4;
        int m0 = mbase + s0;
        const float* src = xg + (size_t)c * T_LEN + m0;
        float v0, v1, v2, v3;
        if (m0 >= 0 && m0 + 3 < T_LEN) {
            float4 v = *(const float4*)src;
            v0 = v.x; v1 = v.y; v2 = v.z; v3 = v.w;
        } else {
            v0 = (m0 + 0 >= 0 && m0 + 0 < T_LEN) ? src[0] : 0.f;
            v1 = (m0 + 1 >= 0 && m0 + 1 < T_LEN) ? src[1] : 0.f;
            v2 = (m0 + 2 >= 0 && m0 + 2 < T_LEN) ? src[2] : 0.f;
            v3 = (m0 + 3 >= 0 && m0 + 3 < T_LEN) ? src[3] : 0.f;
        }
        unsigned p01 = pack_bf2(v0, v1);
        unsigned p23 = pack_bf2(v2, v3);
        xs[(s0 + 0) * 64 + (c ^ (((s0 + 0) & 7) << 3))] = (ushort_t)(p01 & 0xffff);
        xs[(s0 + 1) * 64 + (c ^ (((s0 + 1) & 7) << 3))] = (ushort_t)(p01 >> 16);
        xs[(s0 + 2) * 64 + (c ^ (((s0 + 2) & 7) << 3))] = (ushort_t)(p23 & 0xffff);
        xs[(s0 + 3) * 64 + (c ^ (((s0 + 3) & 7) << 3))] = (ushort_t)(p23 >> 16);
    }
    __syncthreads();

    // ---------------- MFMA: A (taps 3u), L0 (3u+2), L1 (3u+1) over 80-pos window ----------------
    const int lane = tid & 63;
    const int wv   = tid >> 6;       // wave id -> o-tile (16 out-chs)
    const int row  = lane & 15;      // A row (position) == B col (out-ch)
    const int kb   = lane >> 4;      // k-block 0..3

    f32x4 acc[3][5];
    #pragma unroll
    for (int p = 0; p < 3; ++p)
        #pragma unroll
        for (int q = 0; q < 5; ++q)
            acc[p][q] = (f32x4){0.f, 0.f, 0.f, 0.f};

    const int wo = g * 64 + wv * 16 + row;   // global out-channel of this lane's B-col

    #pragma unroll
    for (int u = 0; u < 5; ++u) {
        #pragma unroll
        for (int h = 0; h < 2; ++h) {
            bf16x8 wf0 = *(const bf16x8*)(wbf + ((3 * u + 0) * 128 + wo) * 64 + h * 32 + kb * 8);
            bf16x8 wf1 = {}, wf2 = {};
            if (u < 4) {
                wf1 = *(const bf16x8*)(wbf + ((3 * u + 2) * 128 + wo) * 64 + h * 32 + kb * 8);
                wf2 = *(const bf16x8*)(wbf + ((3 * u + 1) * 128 + wo) * 64 + h * 32 + kb * 8);
            }
            #pragma unroll
            for (int q = 0; q < 5; ++q) {
                int s = 16 * q + row + u;
                const bf16x8 xa = *(const bf16x8*)(xs + s * 64 + ((h * 32 + kb * 8) ^ ((s & 7) << 3)));
                acc[0][q] = __builtin_amdgcn_mfma_f32_16x16x32_bf16(xa, wf0, acc[0][q], 0, 0, 0);
                if (u < 4) {
                    acc[1][q] = __builtin_amdgcn_mfma_f32_16x16x32_bf16(xa, wf1, acc[1][q], 0, 0, 0);
                    acc[2][q] = __builtin_amdgcn_mfma_f32_16x16x32_bf16(xa, wf2, acc[2][q], 0, 0, 0);
                }
            }
        }
    }
    const float bo = bias[wo];
    __syncthreads();   // all waves done reading xs; safe to overwrite with phase data

    // ---------------- dump bias-folded bf16 phase tiles: ph[p][pos][o] ----------------
    #pragma unroll
    for (int p = 0; p < 3; ++p)
        #pragma unroll
        for (int q = 0; q < 5; ++q) {
            unsigned pa = pack_bf2(acc[p][q][0] + bo, acc[p][q][1] + bo);
            unsigned pb = pack_bf2(acc[p][q][2] + bo, acc[p][q][3] + bo);
            int base = p * PH_U16 + (16 * q + kb * 4) * POSTRIDE + wv * 16 + row;
            smem[base + 0 * POSTRIDE] = (ushort_t)(pa & 0xffff);
            smem[base + 1 * POSTRIDE] = (ushort_t)(pa >> 16);
            smem[base + 2 * POSTRIDE] = (ushort_t)(pb & 0xffff);
            smem[base + 3 * POSTRIDE] = (ushort_t)(pb >> 16);
        }
    __syncthreads();

    // ---------------- elementwise epilogue (o-pair u32 reads, lanes over t) ----------------
    const int tl = tid & 63;
    const int wq = tid >> 6;
    const int t  = t0 + tl;
    const ushort_t* phA  = smem;
    const ushort_t* phL0 = smem + PH_U16;
    const ushort_t* phL1 = smem + 2 * PH_U16;
    float* outp = out + ((size_t)b * 128 + (size_t)g * 64) * T_LEN + t;

    if (tile != 0 && tile != 127) {
        // fully interior: s = refl(t-2)-mbase = tl+6, taps s-2..s+2 all valid, no zero-pad max
        const int s = tl + 6;
        for (int i = 0; i < 8; ++i) {
            int o = 2 * wq + 8 * i;
            unsigned a0 = *(const unsigned*)(phA + (s - 2) * POSTRIDE + o);
            unsigned a1 = *(const unsigned*)(phA + (s - 1) * POSTRIDE + o);
            unsigned a2 = *(const unsigned*)(phA + (s    ) * POSTRIDE + o);
            unsigned a3 = *(const unsigned*)(phA + (s + 1) * POSTRIDE + o);
            unsigned a4 = *(const unsigned*)(phA + (s + 2) * POSTRIDE + o);
            unsigned l0a = *(const unsigned*)(phL0 + (s    ) * POSTRIDE + o);
            unsigned l0b = *(const unsigned*)(phL0 + (s + 1) * POSTRIDE + o);
            unsigned l1a = *(const unsigned*)(phL1 + (s    ) * POSTRIDE + o);
            unsigned l1b = *(const unsigned*)(phL1 + (s + 1) * POSTRIDE + o);

            float xm_l = bflo(a2), xm_h = bfhi(a2);
            float um_l = fmaxf(fmaxf(fmaxf(bflo(a0), bflo(a1)), fmaxf(bflo(a3), bflo(a4))), xm_l);
            float um_h = fmaxf(fmaxf(fmaxf(bfhi(a0), bfhi(a1)), fmaxf(bfhi(a3), bfhi(a4))), xm_h);

            float l0al = bflo(l0a), l0bl = bflo(l0b), l1al = bflo(l1a), l1bl = bflo(l1b);
            float l0ah = bfhi(l0a), l0bh = bfhi(l0b), l1ah = bfhi(l1a), l1bh = bfhi(l1b);

            float rl = 2.f * xm_l + um_l + (l0bl + l0al) + qgelu(l0bl - l0al)
                                         + (l1bl + l1al) + qgelu(l1bl - l1al);
            float rh = 2.f * xm_h + um_h + (l0bh + l0ah) + qgelu(l0bh - l0ah)
                                         + (l1bh + l1ah) + qgelu(l1bh - l1ah);
            outp[(size_t)(o    ) * T_LEN] = rl;
            outp[(size_t)(o + 1) * T_LEN] = rh;
        }
    } else {
        // boundary tiles: reflection + zero-padded max
        int  s5[5];
        bool in5[5];
        #pragma unroll
        for (int dt = 0; dt < 5; ++dt) {
            int tp = t + dt - 2;
            in5[dt] = ((unsigned)tp < (unsigned)T_LEN);
            int idx = tp - 2;
            idx = (idx < 0) ? -idx : idx;
            idx = (idx > N_REFL) ? (2 * N_REFL - idx) : idx;
            s5[dt] = idx - mbase;
        }
        const int sC = s5[2];
        for (int i = 0; i < 8; ++i) {
            int o = 2 * wq + 8 * i;
            unsigned av[5];
            #pragma unroll
            for (int dt = 0; dt < 5; ++dt)
                av[dt] = *(const unsigned*)(phA + s5[dt] * POSTRIDE + o);
            unsigned l0a = *(const unsigned*)(phL0 + (sC    ) * POSTRIDE + o);
            unsigned l0b = *(const unsigned*)(phL0 + (sC + 1) * POSTRIDE + o);
            unsigned l1a = *(const unsigned*)(phL1 + (sC    ) * POSTRIDE + o);
            unsigned l1b = *(const unsigned*)(phL1 + (sC + 1) * POSTRIDE + o);

            float xm_l = bflo(av[2]), xm_h = bfhi(av[2]);
            float um_l = -1e30f, um_h = -1e30f;
            #pragma unroll
            for (int dt = 0; dt < 5; ++dt) {
                um_l = fmaxf(um_l, in5[dt] ? bflo(av[dt]) : 0.f);
                um_h = fmaxf(um_h, in5[dt] ? bfhi(av[dt]) : 0.f);
            }
            float l0al = bflo(l0a), l0bl = bflo(l0b), l1al = bflo(l1a), l1bl = bflo(l1b);
            float l0ah = bfhi(l0a), l0bh = bfhi(l0b), l1ah = bfhi(l1a), l1bh = bfhi(l1b);

            float rl = 2.f * xm_l + um_l + (l0bl + l0al) + qgelu(l0bl - l0al)
                                         + (l1bl + l1al) + qgelu(l1bl - l1al);
            float rh = 2.f * xm_h + um_h + (l0bh + l0ah) + qgelu(l0bh - l0ah)
                                         + (l1bh + l1ah) + qgelu(l1bh - l1ah);
            outp[(size_t)(o    ) * T_LEN] = rl;
            outp[(size_t)(o + 1) * T_LEN] = rh;
        }
    }
}

extern "C" void kernel_launch(void* const* d_in, const int* in_sizes, int n_in,
                              void* d_out, int out_size, void* d_ws, size_t ws_size,
                              hipStream_t stream) {
    const float* x    = (const float*)d_in[0];
    const float* w    = (const float*)d_in[1];
    const float* bias = (const float*)d_in[2];
    float* out        = (float*)d_out;
    ushort_t* wbf     = (ushort_t*)d_ws;    // 13*128*64*2 = 212,992 B

    hipLaunchKernelGGL(convert_w_kernel, dim3(416), dim3(256), 0, stream, w, wbf);
    hipLaunchKernelGGL(fused_trconv_kernel, dim3(16 * 2 * 128), dim3(256), 0, stream,
                       x, wbf, bias, out);
}

// Round 3
// 94.361 us; speedup vs baseline: 1.1642x; 1.0330x over previous
//
#include <hip/hip_runtime.h>
#include <hip/hip_bf16.h>

typedef __attribute__((ext_vector_type(4))) float f32x4;
typedef __attribute__((ext_vector_type(8))) short bf16x8;
typedef unsigned short ushort_t;

#define T_LEN 8192
#define N_REFL 8187              // last valid phase index (phase arrays have 8188 elems)
#define TS 64                    // output positions per block
#define WIN 80                   // phase window positions per block
#define XW 88                    // staged x positions per block
#define POSTRIDE 66              // u16 per phase row (boundary path only)
#define PH_U16 (WIN * POSTRIDE)  // 5280 u16 per phase

__device__ __forceinline__ ushort_t f2bf(float f) {
    union { float f; unsigned u; } a; a.f = f;
    unsigned r = a.u + 0x7FFF + ((a.u >> 16) & 1);
    return (ushort_t)(r >> 16);
}

union bf2u { __hip_bfloat162 h; unsigned u; ushort_t s[2]; };

__device__ __forceinline__ unsigned pack_bf2(float a, float b) {
    bf2u x; x.h = __float22bfloat162_rn(make_float2(a, b));  // v_cvt_pk_bf16_f32
    return x.u;
}
__device__ __forceinline__ float bflo(unsigned u) {
    union { unsigned u; float f; } x; x.u = u << 16; return x.f;
}
__device__ __forceinline__ float bfhi(unsigned u) {
    union { unsigned u; float f; } x; x.u = u & 0xffff0000u; return x.f;
}
__device__ __forceinline__ float qgelu(float d) {
    return __fdividef(d, 1.f + __expf(-1.702f * d));
}
__device__ __forceinline__ float rot_lane(float v, int byteIdx) {
    int r = __builtin_amdgcn_ds_bpermute(byteIdx, __builtin_bit_cast(int, v));
    return __builtin_bit_cast(float, r);
}

// Repack w (128, 64, 13) f32 -> wbf[tap][o][c] bf16
__global__ void convert_w_kernel(const float* __restrict__ w, ushort_t* __restrict__ wbf) {
    int idx = blockIdx.x * 256 + threadIdx.x;
    if (idx >= 128 * 64 * 13) return;
    int tap = idx % 13;
    int c   = (idx / 13) & 63;
    int o   = idx / (13 * 64);
    wbf[(tap * 128 + o) * 64 + c] = f2bf(w[idx]);
}

__global__ __launch_bounds__(256, 4)
void fused_trconv_kernel(const float* __restrict__ x, const ushort_t* __restrict__ wbf,
                         const float* __restrict__ bias, float* __restrict__ out) {
    // smem: xs staging (first 11,264 B); boundary tiles also use it for phase dump.
    __shared__ ushort_t smem[3 * PH_U16];   // 31,680 B
    ushort_t* xs = smem;                    // [XW][64] bf16, XOR-swizzled

    const int bx    = blockIdx.x;
    const int tile  = bx & 127;
    const int g     = (bx >> 7) & 1;
    const int b     = bx >> 8;
    const int t0    = tile * TS;
    const int mbase = t0 - 8;
    const int tid   = threadIdx.x;

    // ---------------- stage x[group ch][mbase .. mbase+87] -> LDS bf16 [pos][ch] ----------------
    const float* xg = x + ((size_t)b * 128 + (size_t)g * 64) * T_LEN;
    for (int cid = tid; cid < 64 * (XW / 4); cid += 256) {
        int c  = cid & 63;
        int kc = cid >> 6;
        int s0 = kc * 4;
        int m0 = mbase + s0;
        const float* src = xg + (size_t)c * T_LEN + m0;
        float v0, v1, v2, v3;
        if (m0 >= 0 && m0 + 3 < T_LEN) {
            float4 v = *(const float4*)src;
            v0 = v.x; v1 = v.y; v2 = v.z; v3 = v.w;
        } else {
            v0 = (m0 + 0 >= 0 && m0 + 0 < T_LEN) ? src[0] : 0.f;
            v1 = (m0 + 1 >= 0 && m0 + 1 < T_LEN) ? src[1] : 0.f;
            v2 = (m0 + 2 >= 0 && m0 + 2 < T_LEN) ? src[2] : 0.f;
            v3 = (m0 + 3 >= 0 && m0 + 3 < T_LEN) ? src[3] : 0.f;
        }
        unsigned p01 = pack_bf2(v0, v1);
        unsigned p23 = pack_bf2(v2, v3);
        xs[(s0 + 0) * 64 + (c ^ (((s0 + 0) & 7) << 3))] = (ushort_t)(p01 & 0xffff);
        xs[(s0 + 1) * 64 + (c ^ (((s0 + 1) & 7) << 3))] = (ushort_t)(p01 >> 16);
        xs[(s0 + 2) * 64 + (c ^ (((s0 + 2) & 7) << 3))] = (ushort_t)(p23 & 0xffff);
        xs[(s0 + 3) * 64 + (c ^ (((s0 + 3) & 7) << 3))] = (ushort_t)(p23 >> 16);
    }
    __syncthreads();

    // ---------------- MFMA: A (taps 3u), L0 (3u+2), L1 (3u+1) over 80-pos window ----------------
    const int lane = tid & 63;
    const int wv   = tid >> 6;       // wave id -> o-tile (16 out-chs)
    const int row  = lane & 15;      // A row (position) == B col (out-ch)
    const int kb   = lane >> 4;      // k-block 0..3 -> C rows 4kb..4kb+3

    f32x4 accA[5], accL0[5], accL1[5];
    #pragma unroll
    for (int q = 0; q < 5; ++q) {
        accA[q] = (f32x4){0.f, 0.f, 0.f, 0.f};
        accL0[q] = (f32x4){0.f, 0.f, 0.f, 0.f};
        accL1[q] = (f32x4){0.f, 0.f, 0.f, 0.f};
    }

    const int wo = g * 64 + wv * 16 + row;   // global out-channel of this lane's B-col

    #pragma unroll
    for (int u = 0; u < 5; ++u) {
        #pragma unroll
        for (int h = 0; h < 2; ++h) {
            bf16x8 wf0 = *(const bf16x8*)(wbf + ((3 * u + 0) * 128 + wo) * 64 + h * 32 + kb * 8);
            bf16x8 wf1 = {}, wf2 = {};
            if (u < 4) {
                wf1 = *(const bf16x8*)(wbf + ((3 * u + 2) * 128 + wo) * 64 + h * 32 + kb * 8);
                wf2 = *(const bf16x8*)(wbf + ((3 * u + 1) * 128 + wo) * 64 + h * 32 + kb * 8);
            }
            #pragma unroll
            for (int q = 0; q < 5; ++q) {
                int s = 16 * q + row + u;
                const bf16x8 xa = *(const bf16x8*)(xs + s * 64 + ((h * 32 + kb * 8) ^ ((s & 7) << 3)));
                accA[q] = __builtin_amdgcn_mfma_f32_16x16x32_bf16(xa, wf0, accA[q], 0, 0, 0);
                if (u < 4) {
                    accL0[q] = __builtin_amdgcn_mfma_f32_16x16x32_bf16(xa, wf1, accL0[q], 0, 0, 0);
                    accL1[q] = __builtin_amdgcn_mfma_f32_16x16x32_bf16(xa, wf2, accL1[q], 0, 0, 0);
                }
            }
        }
    }
    const float bo = bias[wo];

    if (tile != 0 && tile != 127) {
        // ================= interior: in-register epilogue (no LDS, no barriers) =================
        // Lane holds phase values at window positions P = 16q + 4kb + r for out-ch `wo`.
        // Output t = t0 + P - 6 for P in [6, 69]. Needs A[P-2..P+2], L*[P], L*[P+1] (same o).
        const int upIdx = ((lane + 16) & 63) << 2;   // pull from lane+16 (kb+1, q-wrap)
        const int dnIdx = ((lane + 48) & 63) << 2;   // pull from lane-16 (kb-1, q-wrap)

        float u0[6], u1[6], d2m[5], d3m[5], lu[6], lv[6];
        #pragma unroll
        for (int q = 0; q < 5; ++q) {
            u0[q] = rot_lane(accA[q][0], upIdx);
            u1[q] = rot_lane(accA[q][1], upIdx);
            d2m[q] = rot_lane(accA[q][2], dnIdx);
            d3m[q] = rot_lane(accA[q][3], dnIdx);
            lu[q] = rot_lane(accL0[q][0], upIdx);
            lv[q] = rot_lane(accL1[q][0], upIdx);
        }
        u0[5] = 0.f; u1[5] = 0.f; lu[5] = 0.f; lv[5] = 0.f;

        const bool kbLT3 = (kb < 3);
        const bool kbGT0 = (kb > 0);
        const float c7bo = 7.f * bo;
        float* outBase = out + ((size_t)(b * 128 + wo)) * T_LEN + (t0 - 6 + 4 * kb);

        #pragma unroll
        for (int q = 0; q < 5; ++q) {
            #pragma unroll
            for (int r = 0; r < 4; ++r) {
                float A0 = accA[q][r];
                float Ap1 = (r < 3) ? accA[q][r + 1] : (kbLT3 ? u0[q] : u0[q + 1]);
                float Ap2 = (r == 0) ? accA[q][2]
                          : (r == 1) ? accA[q][3]
                          : (r == 2) ? (kbLT3 ? u0[q] : u0[q + 1])
                                     : (kbLT3 ? u1[q] : u1[q + 1]);
                float Am1 = (r > 0) ? accA[q][r - 1]
                                    : (kbGT0 ? d3m[q] : (q > 0 ? d3m[q - 1] : 0.f));
                float Am2 = (r == 2) ? accA[q][0]
                          : (r == 3) ? accA[q][1]
                          : (r == 1) ? (kbGT0 ? d3m[q] : (q > 0 ? d3m[q - 1] : 0.f))
                                     : (kbGT0 ? d2m[q] : (q > 0 ? d2m[q - 1] : 0.f));
                float L0a = accL0[q][r];
                float L0b = (r < 3) ? accL0[q][r + 1] : (kbLT3 ? lu[q] : lu[q + 1]);
                float L1a = accL1[q][r];
                float L1b = (r < 3) ? accL1[q][r + 1] : (kbLT3 ? lv[q] : lv[q + 1]);

                float um = fmaxf(fmaxf(fmaxf(Am2, Am1), fmaxf(Ap1, Ap2)), A0);
                float res = 2.f * A0 + um + c7bo + (L0b + L0a) + (L1b + L1a)
                          + qgelu(L0b - L0a) + qgelu(L1b - L1a);

                bool ok = true;
                if (q == 0) ok = (4 * kb + r) >= 6;
                if (q == 4) ok = (4 * kb + r) <= 5;
                if (ok) outBase[16 * q + r] = res;
            }
        }
    } else {
        // ================= boundary tiles (2 of 128): LDS phase path =================
        __syncthreads();   // all waves done reading xs; safe to overwrite
        #pragma unroll
        for (int q = 0; q < 5; ++q) {
            #pragma unroll
            for (int p = 0; p < 3; ++p) {
                const f32x4& a = (p == 0) ? accA[q] : (p == 1) ? accL0[q] : accL1[q];
                unsigned pa = pack_bf2(a[0] + bo, a[1] + bo);
                unsigned pb = pack_bf2(a[2] + bo, a[3] + bo);
                int base = p * PH_U16 + (16 * q + kb * 4) * POSTRIDE + wv * 16 + row;
                smem[base + 0 * POSTRIDE] = (ushort_t)(pa & 0xffff);
                smem[base + 1 * POSTRIDE] = (ushort_t)(pa >> 16);
                smem[base + 2 * POSTRIDE] = (ushort_t)(pb & 0xffff);
                smem[base + 3 * POSTRIDE] = (ushort_t)(pb >> 16);
            }
        }
        __syncthreads();

        const int tl = tid & 63;
        const int wq = tid >> 6;
        const int t  = t0 + tl;
        const ushort_t* phA  = smem;
        const ushort_t* phL0 = smem + PH_U16;
        const ushort_t* phL1 = smem + 2 * PH_U16;
        float* outp = out + ((size_t)b * 128 + (size_t)g * 64) * T_LEN + t;

        int  s5[5];
        bool in5[5];
        #pragma unroll
        for (int dt = 0; dt < 5; ++dt) {
            int tp = t + dt - 2;
            in5[dt] = ((unsigned)tp < (unsigned)T_LEN);
            int idx = tp - 2;
            idx = (idx < 0) ? -idx : idx;
            idx = (idx > N_REFL) ? (2 * N_REFL - idx) : idx;
            s5[dt] = idx - mbase;
        }
        const int sC = s5[2];
        for (int i = 0; i < 8; ++i) {
            int o = 2 * wq + 8 * i;
            unsigned av[5];
            #pragma unroll
            for (int dt = 0; dt < 5; ++dt)
                av[dt] = *(const unsigned*)(phA + s5[dt] * POSTRIDE + o);
            unsigned l0a = *(const unsigned*)(phL0 + (sC    ) * POSTRIDE + o);
            unsigned l0b = *(const unsigned*)(phL0 + (sC + 1) * POSTRIDE + o);
            unsigned l1a = *(const unsigned*)(phL1 + (sC    ) * POSTRIDE + o);
            unsigned l1b = *(const unsigned*)(phL1 + (sC + 1) * POSTRIDE + o);

            float xm_l = bflo(av[2]), xm_h = bfhi(av[2]);
            float um_l = -1e30f, um_h = -1e30f;
            #pragma unroll
            for (int dt = 0; dt < 5; ++dt) {
                um_l = fmaxf(um_l, in5[dt] ? bflo(av[dt]) : 0.f);
                um_h = fmaxf(um_h, in5[dt] ? bfhi(av[dt]) : 0.f);
            }
            float l0al = bflo(l0a), l0bl = bflo(l0b), l1al = bflo(l1a), l1bl = bflo(l1b);
            float l0ah = bfhi(l0a), l0bh = bfhi(l0b), l1ah = bfhi(l1a), l1bh = bfhi(l1b);

            float rl = 2.f * xm_l + um_l + (l0bl + l0al) + qgelu(l0bl - l0al)
                                         + (l1bl + l1al) + qgelu(l1bl - l1al);
            float rh = 2.f * xm_h + um_h + (l0bh + l0ah) + qgelu(l0bh - l0ah)
                                         + (l1bh + l1ah) + qgelu(l1bh - l1ah);
            outp[(size_t)(o    ) * T_LEN] = rl;
            outp[(size_t)(o + 1) * T_LEN] = rh;
        }
    }
}

extern "C" void kernel_launch(void* const* d_in, const int* in_sizes, int n_in,
                              void* d_out, int out_size, void* d_ws, size_t ws_size,
                              hipStream_t stream) {
    const float* x    = (const float*)d_in[0];
    const float* w    = (const float*)d_in[1];
    const float* bias = (const float*)d_in[2];
    float* out        = (float*)d_out;
    ushort_t* wbf     = (ushort_t*)d_ws;    // 13*128*64*2 = 212,992 B

    hipLaunchKernelGGL(convert_w_kernel, dim3(416), dim3(256), 0, stream, w, wbf);
    hipLaunchKernelGGL(fused_trconv_kernel, dim3(16 * 2 * 128), dim3(256), 0, stream,
                       x, wbf, bias, out);
}